// Round 10
// baseline (288.382 us; speedup 1.0000x reference)
//
#include <hip/hip_runtime.h>
#include <hip/hip_bf16.h>

#define L 2048
#define D 2048
#define NH 32
#define NKV 8
#define HD 64

typedef unsigned short u16;
typedef __attribute__((ext_vector_type(8))) short bf16x8;   // 8 bf16 in 4 VGPRs
typedef __attribute__((ext_vector_type(4))) short bf16x4;   // 4 bf16 in 2 VGPRs
typedef __attribute__((ext_vector_type(4))) float f32x4;

#define QSCALE 0.1803368801f   // 0.125 * log2(e): S comes out in log2 domain

// 16x16x16 bf16 MFMA (K=16): the _1k builtin, called directly (r8-proven).
__device__ __forceinline__ f32x4 mfma16(bf16x4 a, bf16x4 b, f32x4 c) {
    return __builtin_amdgcn_mfma_f32_16x16x16bf16_1k(a, b, c, 0, 0, 0);
}

// Panel layout for GEMM operands: [dim0/128][k/32][128][32] (u16), so one
// 128x32 sub-tile = 8KB contiguous.
#define PANEL_OFF(d0, k) ((((size_t)((d0) >> 7) * 64 + ((k) >> 5)) << 12) + (((d0) & 127) << 5) + ((k) & 31))

__device__ __forceinline__ u16 f2bf(float x) {
    __hip_bfloat16 b = __float2bfloat16(x);
    return *reinterpret_cast<u16*>(&b);
}

// Async global->LDS, 16B per lane. Global src address is PER-LANE; LDS dest
// is wave-uniform base + lane*16.
__device__ __forceinline__ void gload_lds16(const void* g, void* l) {
    __builtin_amdgcn_global_load_lds(
        (const __attribute__((address_space(1))) unsigned int*)g,
        (__attribute__((address_space(3))) unsigned int*)l, 16, 0, 0);
}

// ---------------------------------------------------------------------------
// Fused prep, r10 rewrite (was ~50-70us by budget decomposition; floor ~15):
// z=0..3: weight transpose fp32 [2048][C] -> bf16 PANEL, 64x64 tiles,
//         float4 loads (coalesced 256B/row-quarter), LDS [64][65] fp32
//         (stride 65 -> conflict-free transpose reads), 16 elems/thread,
//         2x bf16x8 panel stores (16 u16 contiguous within a k-block).
// z=4: x cast, 4x float4 per thread.
// Grid: dim3(32,32,5) = 5120 blocks (was 20480 with 75% idle in z=1,2).
// ---------------------------------------------------------------------------
__global__ __launch_bounds__(256) void prep_kernel(
    const float* __restrict__ x, u16* __restrict__ xb,
    const float* __restrict__ wq, const float* __restrict__ wk,
    const float* __restrict__ wv, const float* __restrict__ wo,
    u16* __restrict__ wqkvT, u16* __restrict__ woT)
{
    const int z = blockIdx.z;
    const int tid = threadIdx.x;
    if (z == 4) {                                  // cast x -> panels
        const int base = (blockIdx.y * 32 + blockIdx.x) * 1024 + tid;
#pragma unroll
        for (int k = 0; k < 4; ++k) {
            const int i = base + k * 256;          // float4 idx, coalesced
            const int e = i * 4;
            const int row = e >> 11, k0 = e & 2047;
            float4 v = ((const float4*)x)[i];
            ushort4 o;
            o.x = f2bf(v.x); o.y = f2bf(v.y); o.z = f2bf(v.z); o.w = f2bf(v.w);
            *(ushort4*)&xb[PANEL_OFF(row, k0)] = o;
        }
        return;
    }
    const float* src; u16* dst; int C;
    if (z == 0)      { src = wq; dst = wqkvT;                           C = 2048; }
    else if (z == 1) { src = wk; dst = wqkvT + (size_t)2048 * 2048;     C = 512;  }
    else if (z == 2) { src = wv; dst = wqkvT + (size_t)2560 * 2048;     C = 512;  }
    else             { src = wo; dst = woT;                             C = 2048; }
    const int c0 = blockIdx.x * 64;                // n-block (weight col)
    if (c0 >= C) return;
    const int r0 = blockIdx.y * 64;                // k-block (contraction)
    __shared__ float tile[64][65];                 // tile[a][b] = src[r0+a][c0+b]
    {
        const int b4 = (tid & 15) * 4, ty = tid >> 4;
#pragma unroll
        for (int i = 0; i < 4; ++i) {
            const int a = ty + i * 16;
            float4 v = *(const float4*)&src[(size_t)(r0 + a) * C + c0 + b4];
            tile[a][b4] = v.x; tile[a][b4 + 1] = v.y;
            tile[a][b4 + 2] = v.z; tile[a][b4 + 3] = v.w;
        }
    }
    __syncthreads();
    {
        const int j = tid & 63, h16 = (tid >> 6) * 16;   // n-local, k-quarter
        u16 buf[16];
#pragma unroll
        for (int t = 0; t < 16; ++t) buf[t] = f2bf(tile[h16 + t][j]);
        u16* d = &dst[PANEL_OFF(c0 + j, r0 + h16)];      // 16 u16 contiguous
        *(bf16x8*)d       = *(bf16x8*)&buf[0];
        *(bf16x8*)(d + 8) = *(bf16x8*)&buf[8];
    }
}

// ---------------------------------------------------------------------------
// 4-wave 128x128 MFMA GEMM on PANEL-layout operands, r10 sync restructure:
// 8 LDS buffers (128KB), ONE barrier + counted vmcnt(16) per 64-K period,
// NO lgkmcnt(0) drain (compiler inserts fine-grained lgkm waits before
// dependent MFMAs; all ds_reads are register-consumed before the wave
// reaches the next barrier, so the single barrier orders write-after-read).
//
// Rotation: period t reads bufs (2t)%8,(2t+1)%8; prefetches subs 2t+6,2t+7
// into bufs (2t+6)%8 == bufs read at period t-1 (barrier-protected).
// Prologue: subs 0..5 (24 DMAs). Steady state: wait vmcnt(16) -> subs
// 2t,2t+1 done, 4 subs in flight; issue 8 more. Issue-to-consume = 3
// periods (~>=900cyc) covers HBM latency. Cost: 128KB LDS -> 1 block/CU
// (QKV loses its 2nd resident block; bet: depth+fewer drains > lost TLP).
// ---------------------------------------------------------------------------
#define VT_LDS 72   // u16 stride for V-transpose scratch (144B, 16B-aligned)

template <int MODE>
__global__ __launch_bounds__(256) void gemm4w_kernel(
    const u16* __restrict__ A, const u16* __restrict__ Bt, void* __restrict__ Cout,
    int N, int K, const float* __restrict__ fc, const float* __restrict__ fs,
    u16* __restrict__ vt)
{
    __shared__ __align__(16) u16 As[8][128 * 32];
    __shared__ __align__(16) u16 Bs[8][128 * 32];
    const int tid = threadIdx.x;
    const int w = tid >> 6, lane = tid & 63;

    // bijective XCD-aware block swizzle (both grids have nwg % 8 == 0)
    const int nwg = (int)(gridDim.x * gridDim.y);
    int bid = (int)blockIdx.y * (int)gridDim.x + (int)blockIdx.x;
    bid = (bid & 7) * (nwg >> 3) + (bid >> 3);
    const int m0 = (bid / (int)gridDim.x) * 128, n0 = (bid % (int)gridDim.x) * 128;

    const int l15 = lane & 15, quad = lane >> 4, q8 = quad * 8;
    const int wr = (w >> 1) * 64, wc = (w & 1) * 64;    // wave's C-quadrant
    const int l8 = lane * 8;                            // u16 offset of lane's 16B
    const int wch = w * 1024;                           // wave's 2KB chunk of 8KB sub-tile

    // panel bases: sub-tile s of this block's panels is 4096 u16 at s*4096
    const u16* pa = A  + ((size_t)(m0 >> 7) * (K / 32) << 12);
    const u16* pb = Bt + ((size_t)(n0 >> 7) * (K / 32) << 12);

    f32x4 acc[4][4];
#pragma unroll
    for (int i = 0; i < 4; ++i)
#pragma unroll
        for (int j = 0; j < 4; ++j) acc[i][j] = (f32x4){0.f, 0.f, 0.f, 0.f};

    const int nSub = K / 32;          // 32-K sub-tiles
    const int nOut = nSub / 2;        // wait-periods (BK=64)
    // prologue: subs 0..5 into bufs 0..5 (24 DMAs in flight)
#pragma unroll
    for (int s = 0; s < 6; ++s) {
        const size_t so = (size_t)s << 12;
        gload_lds16(pa + so + wch + l8,       &As[s][wch]);
        gload_lds16(pa + so + wch + 512 + l8, &As[s][wch + 512]);
        gload_lds16(pb + so + wch + l8,       &Bs[s][wch]);
        gload_lds16(pb + so + wch + 512 + l8, &Bs[s][wch + 512]);
    }
    int c0i = 0;                       // buf idx of this period's first sub (0,2,4,6,..)
    for (int it = 0; it < nOut; ++it) {
        asm volatile("s_waitcnt vmcnt(16)" ::: "memory");  // subs 2t,2t+1 resident
        asm volatile("s_barrier" ::: "memory");            // ..for all waves
        {   // prefetch subs 2t+6, 2t+7 into bufs read at period t-1
            const int pi0 = (c0i == 0) ? 6 : c0i - 2;
            const int sp0 = 2 * it + 6, sp1 = 2 * it + 7;
            const size_t k0 = (size_t)((sp0 < nSub) ? sp0 : 0) << 12;  // wrap: dummy
            const size_t k1 = (size_t)((sp1 < nSub) ? sp1 : 0) << 12;
            gload_lds16(pa + k0 + wch + l8,       &As[pi0][wch]);
            gload_lds16(pa + k0 + wch + 512 + l8, &As[pi0][wch + 512]);
            gload_lds16(pb + k0 + wch + l8,       &Bs[pi0][wch]);
            gload_lds16(pb + k0 + wch + 512 + l8, &Bs[pi0][wch + 512]);
            gload_lds16(pa + k1 + wch + l8,       &As[pi0 + 1][wch]);
            gload_lds16(pa + k1 + wch + 512 + l8, &As[pi0 + 1][wch + 512]);
            gload_lds16(pb + k1 + wch + l8,       &Bs[pi0 + 1][wch]);
            gload_lds16(pb + k1 + wch + 512 + l8, &Bs[pi0 + 1][wch + 512]);
        }
        const int cb0 = c0i, cb1 = c0i + 1;
        {   // sub-tile 0: 8 ds_reads + 16 MFMA (compiler inserts fine lgkm waits)
            bf16x8 a0[4], b0v[4];
#pragma unroll
            for (int t = 0; t < 4; ++t) {
                a0[t]  = *(const bf16x8*)&As[cb0][(wr + t * 16 + l15) * 32 + q8];
                b0v[t] = *(const bf16x8*)&Bs[cb0][(wc + t * 16 + l15) * 32 + q8];
            }
            __builtin_amdgcn_s_setprio(1);
#pragma unroll
            for (int i = 0; i < 4; ++i)
#pragma unroll
                for (int j = 0; j < 4; ++j)
                    acc[i][j] = __builtin_amdgcn_mfma_f32_16x16x32_bf16(a0[i], b0v[j], acc[i][j], 0, 0, 0);
            __builtin_amdgcn_s_setprio(0);
        }
        {   // sub-tile 1
            bf16x8 a1[4], b1v[4];
#pragma unroll
            for (int t = 0; t < 4; ++t) {
                a1[t]  = *(const bf16x8*)&As[cb1][(wr + t * 16 + l15) * 32 + q8];
                b1v[t] = *(const bf16x8*)&Bs[cb1][(wc + t * 16 + l15) * 32 + q8];
            }
            __builtin_amdgcn_s_setprio(1);
#pragma unroll
            for (int i = 0; i < 4; ++i)
#pragma unroll
                for (int j = 0; j < 4; ++j)
                    acc[i][j] = __builtin_amdgcn_mfma_f32_16x16x32_bf16(a1[i], b1v[j], acc[i][j], 0, 0, 0);
            __builtin_amdgcn_s_setprio(0);
        }
        c0i = (c0i == 6) ? 0 : c0i + 2;
    }

    if (MODE == 0) {
        float* C = (float*)Cout;
#pragma unroll
        for (int i = 0; i < 4; ++i)
#pragma unroll
            for (int j = 0; j < 4; ++j)
#pragma unroll
                for (int r = 0; r < 4; ++r)
                    C[(size_t)(m0 + wr + i * 16 + quad * 4 + r) * N + n0 + wc + j * 16 + l15] = acc[i][j][r];
    } else {
        __syncthreads();                       // loop done everywhere; LDS reusable
        u16* O = (u16*)Cout;
        const int vc0 = n0 + wc;               // wave's first output column
        if (vc0 < 2560) {                      // Q or K region: RoPE + row store
            const float scl = (vc0 < 2048) ? QSCALE : 1.0f;   // q only
            const int odd = l15 & 1;
#pragma unroll
            for (int i = 0; i < 4; ++i)
#pragma unroll
                for (int j = 0; j < 4; ++j)
#pragma unroll
                    for (int r = 0; r < 4; ++r) {
                        const int row = m0 + wr + i * 16 + quad * 4 + r;
                        const int col = vc0 + j * 16 + l15;
                        float v = acc[i][j][r];
                        const int i2 = (j * 16 + l15) >> 1;   // head-dim pair (vc0 is 64-aligned)
                        const float c = fc[row * 32 + i2], s = fs[row * 32 + i2];
                        const float p = __shfl_xor(v, 1);
                        float o = (odd ? (p * s + v * c) : (v * c - p * s)) * scl;
                        O[(size_t)row * 3072 + col] = f2bf(o);
                    }
        } else {                               // V region: transpose -> vt via LDS
            u16* ws_ = (w < 2 ? (u16*)As : (u16*)Bs) + (w & 1) * (64 * VT_LDS);
#pragma unroll
            for (int i = 0; i < 4; ++i)
#pragma unroll
                for (int j = 0; j < 4; ++j)
#pragma unroll
                    for (int r = 0; r < 4; ++r)
                        ws_[(j * 16 + l15) * VT_LDS + i * 16 + quad * 4 + r] = f2bf(acc[i][j][r]);
            // ws_ is [64 vcols][64 seq]; read rows coalesced, write vt rows
#pragma unroll
            for (int t = 0; t < 8; ++t) {
                const int vr = t * 8 + (lane >> 3);
                const int c8 = (lane & 7) * 8;
                bf16x8 vv = *(const bf16x8*)&ws_[vr * VT_LDS + c8];
                *(bf16x8*)&vt[(size_t)(vc0 - 2560 + vr) * 2048 + m0 + wr + c8] = vv;
            }
        }
    }
}

// ---------------------------------------------------------------------------
// MFMA flash attention: r9-passing version, UNCHANGED.
// ---------------------------------------------------------------------------
#define ATT_STEP(CVAL, CB)                                                     \
    {                                                                          \
        gload_lds16(pk0, &Ks[(CB) ^ 1][(w * 16) * 64]);                        \
        gload_lds16(pk1, &Ks[(CB) ^ 1][(w * 16 + 8) * 64]);                    \
        gload_lds16(pv0, &Vs[(CB) ^ 1][(w * 16) * 64]);                        \
        gload_lds16(pv1, &Vs[(CB) ^ 1][(w * 16 + 8) * 64]);                    \
        pk0 += 64 * 3072; pk1 += 64 * 3072; pv0 += 64; pv1 += 64;              \
        asm volatile("s_waitcnt vmcnt(4)" ::: "memory");                       \
        asm volatile("s_barrier" ::: "memory");                                \
        const char* KB = (const char*)Ks + (CB) * 8192;                        \
        const char* VB = (const char*)Vs + (CB) * 8192;                        \
        f32x4 s[4];                                                            \
        __builtin_amdgcn_s_setprio(1);                                         \
        _Pragma("unroll")                                                      \
        for (int kt = 0; kt < 4; ++kt) {                                       \
            bf16x8 b0 = *(const bf16x8*)(KB + kt * 2048 + aK);                 \
            bf16x8 b1 = *(const bf16x8*)(KB + kt * 2048 + aK2);                \
            f32x4 t = (f32x4){0.f, 0.f, 0.f, 0.f};                             \
            t = __builtin_amdgcn_mfma_f32_16x16x32_bf16(b0, qa[0], t, 0, 0, 0);\
            t = __builtin_amdgcn_mfma_f32_16x16x32_bf16(b1, qa[1], t, 0, 0, 0);\
            s[kt] = t;                                                         \
        }                                                                      \
        __builtin_amdgcn_s_setprio(0);                                         \
        if ((CVAL) == tile) {                                                  \
            _Pragma("unroll")                                                  \
            for (int kt = 0; kt < 4; ++kt)                                     \
                _Pragma("unroll")                                              \
                for (int r = 0; r < 4; ++r)                                    \
                    if (kt * 16 + quad * 4 + r > w * 16 + l15)                 \
                        s[kt][r] = -1e30f;                                     \
        }                                                                      \
        float mx = fmaxf(fmaxf(fmaxf(s[0][0], s[0][1]), fmaxf(s[0][2], s[0][3])), \
                         fmaxf(fmaxf(s[1][0], s[1][1]), fmaxf(s[1][2], s[1][3]))); \
        mx = fmaxf(mx, fmaxf(fmaxf(fmaxf(s[2][0], s[2][1]), fmaxf(s[2][2], s[2][3])), \
                             fmaxf(fmaxf(s[3][0], s[3][1]), fmaxf(s[3][2], s[3][3])))); \
        mx = fmaxf(mx, __shfl_xor(mx, 16));                                    \
        mx = fmaxf(mx, __shfl_xor(mx, 32));                                    \
        const bool resc = !__all(mx <= m_run + 8.f);                           \
        float aL = 1.f;                                                        \
        if (resc) {                                                            \
            const float mn = fmaxf(m_run, mx);                                 \
            aL = exp2f(m_run - mn);                                            \
            m_run = mn;                                                        \
        }                                                                      \
        _Pragma("unroll")                                                      \
        for (int kt = 0; kt < 4; ++kt)                                         \
            _Pragma("unroll")                                                  \
            for (int r = 0; r < 4; ++r) s[kt][r] = exp2f(s[kt][r] - m_run);    \
        float rsum = 0.f;                                                      \
        _Pragma("unroll")                                                      \
        for (int kt = 0; kt < 4; ++kt)                                         \
            _Pragma("unroll")                                                  \
            for (int r = 0; r < 4; ++r) rsum += s[kt][r];                      \
        rsum += __shfl_xor(rsum, 16);                                          \
        rsum += __shfl_xor(rsum, 32);                                          \
        l_run = resc ? (l_run * aL + rsum) : (l_run + rsum);                   \
        bf16x4 pbf[4];                                                         \
        _Pragma("unroll")                                                      \
        for (int kt = 0; kt < 4; ++kt) {                                       \
            unsigned int lo, hi;                                               \
            asm("v_cvt_pk_bf16_f32 %0, %1, %2" : "=v"(lo) : "v"(s[kt][0]), "v"(s[kt][1])); \
            asm("v_cvt_pk_bf16_f32 %0, %1, %2" : "=v"(hi) : "v"(s[kt][2]), "v"(s[kt][3])); \
            union { unsigned int u[2]; bf16x4 v; } cv;                         \
            cv.u[0] = lo; cv.u[1] = hi;                                        \
            pbf[kt] = cv.v;                                                    \
        }                                                                      \
        if (resc) {                                                            \
            _Pragma("unroll")                                                  \
            for (int r = 0; r < 4; ++r) {                                      \
                const float aQ = __shfl(aL, (quad << 4) + (quad << 2) + r);    \
                O[0][r] *= aQ; O[1][r] *= aQ; O[2][r] *= aQ; O[3][r] *= aQ;    \
            }                                                                  \
        }                                                                      \
        __builtin_amdgcn_s_setprio(1);                                         \
        _Pragma("unroll")                                                      \
        for (int kt = 0; kt < 4; ++kt) {                                       \
            const int aVk = aV ^ (kt * 32);                                    \
            _Pragma("unroll")                                                  \
            for (int dt = 0; dt < 4; ++dt) {                                   \
                bf16x4 vf = *(const bf16x4*)(VB + dt * 2048 + aVk);            \
                O[dt] = mfma16(pbf[kt], vf, O[dt]);                            \
            }                                                                  \
        }                                                                      \
        __builtin_amdgcn_s_setprio(0);                                         \
        asm volatile("s_barrier" ::: "memory");                                \
    }

__global__ __launch_bounds__(256) void attn_mfma_kernel(
    const u16* __restrict__ qkv,  // [2048][3072] bf16: q|k|v
    const u16* __restrict__ vt,   // [512][2048] bf16 (V^T)
    u16* __restrict__ ab)         // panel-layout bf16 [16][64][128][32]
{
    __shared__ __align__(16) u16 Ks[2][64 * 64];   // linear, swizzled content
    __shared__ __align__(16) u16 Vs[2][64 * 64];

    const int h = blockIdx.x;
    const int tile = (int)gridDim.y - 1 - (int)blockIdx.y;  // big tiles first
    const int gkv = h >> 2;
    const int tid = threadIdx.x;
    const int w = tid >> 6, lane = tid & 63;
    const int l15 = lane & 15, quad = lane >> 4;
    const int q0 = tile * 64 + w * 16;

    // staging geometry (r5): wave w stages rows [w*16, w*16+16) of K and V.
    const int srow = lane >> 3, schunk = lane & 7;
    const int r0_ = w * 16 + srow, r1_ = r0_ + 8;
    const int c0_ = (schunk ^ (r0_ & 7)) * 8, c1_ = (schunk ^ (r1_ & 7)) * 8;

    // DMA source pointers: point at the NEXT tile to prefetch; bumped by
    // constant strides each STEP. Final STEP prefetches one tile past the
    // end -- lands in allocated workspace, never consumed.
    const u16* pk0 = qkv + 2048 + gkv * HD + (size_t)r0_ * 3072 + c0_;
    const u16* pk1 = qkv + 2048 + gkv * HD + (size_t)r1_ * 3072 + c1_;
    const u16* pv0 = vt + (size_t)(gkv * HD + r0_) * 2048 + c0_;
    const u16* pv1 = vt + (size_t)(gkv * HD + r1_) * 2048 + c1_;

    // hoisted per-lane LDS byte-address regs (within one 8KB buffer):
    const int kx = l15 & 7;
    const int aK  = l15 * 128 + ((quad ^ kx) * 16);            // K b128, lo half
    const int aK2 = aK ^ 64;                                   // (quad+4)^kx
    const int aV  = l15 * 128 + (((quad >> 1) ^ kx) * 16) + ((quad & 1) * 8);  // V b64, kt=0

    bf16x8 qa[2];
    {
        const u16* qrow = qkv + (size_t)(q0 + l15) * 3072 + h * HD + quad * 8;
        qa[0] = *(const bf16x8*)(qrow);
        qa[1] = *(const bf16x8*)(qrow + 32);
    }
    f32x4 O[4];
#pragma unroll
    for (int i = 0; i < 4; ++i) O[i] = (f32x4){0.f, 0.f, 0.f, 0.f};
    float m_run = -1e30f;      // softmax side: row l15
    float l_run = 0.f;         // softmax side: row l15 (scalar)

    // prologue: tile 0 into buf 0 (4 DMAs/wave); then bump to tile 1
    gload_lds16(pk0, &Ks[0][(w * 16) * 64]);
    gload_lds16(pk1, &Ks[0][(w * 16 + 8) * 64]);
    gload_lds16(pv0, &Vs[0][(w * 16) * 64]);
    gload_lds16(pv1, &Vs[0][(w * 16 + 8) * 64]);
    pk0 += 64 * 3072; pk1 += 64 * 3072; pv0 += 64; pv1 += 64;

    for (int c = 0; c <= tile; c += 2) {
        ATT_STEP(c, 0)
        if (c + 1 <= tile) {
            ATT_STEP(c + 1, 1)
        }
    }

#pragma unroll
    for (int r = 0; r < 4; ++r) {
        // l for qrow=quad*4+r lives at lane quad*20+r (l15 side -> quad side)
        const float lq = __shfl(l_run, (quad << 4) + (quad << 2) + r);
        const float inv = 1.0f / lq;
        const int q = q0 + quad * 4 + r;
        const int pbase = ((q >> 7) << 18) + ((q & 127) << 5);   // 32-bit panel math
#pragma unroll
        for (int dt = 0; dt < 4; ++dt) {
            const int col = h * HD + dt * 16 + l15;
            ab[pbase + ((col >> 5) << 12) + (col & 31)] = f2bf(O[dt][r] * inv);
        }
    }
}

// ---------------------------------------------------------------------------
extern "C" void kernel_launch(void* const* d_in, const int* in_sizes, int n_in,
                              void* d_out, int out_size, void* d_ws, size_t ws_size,
                              hipStream_t stream)
{
    const float* x  = (const float*)d_in[0];
    const float* wq = (const float*)d_in[1];
    const float* wk = (const float*)d_in[2];
    const float* wv = (const float*)d_in[3];
    const float* wo = (const float*)d_in[4];
    const float* fc = (const float*)d_in[5];
    const float* fs = (const float*)d_in[6];
    // d_in[7] = mask: unused (hard causal == -1e9 additive path in fp32)
    float* out = (float*)d_out;

    // Workspace 50 MB:
    // xb 8MB | wqkvT 12MB | woT 8MB | qkv_bf 12MB | vt 2MB | ab 8MB
    // xb, wqkvT, woT, ab are PANEL layout; qkv_bf, vt plain.
    u16* xb     = (u16*)d_ws;
    u16* wqkvT  = xb     + (size_t)2048 * 2048;
    u16* woT    = wqkvT  + (size_t)3072 * 2048;
    u16* qkv_bf = woT    + (size_t)2048 * 2048;
    u16* vt     = qkv_bf + (size_t)2048 * 3072;
    u16* ab     = vt     + (size_t)512 * 2048;

    // prep: 4 weight transposes + x cast in one dispatch (panel outputs)
    prep_kernel<<<dim3(32, 32, 5), 256, 0, stream>>>(x, xb, wq, wk, wv, wo, wqkvT, woT);

    // QKV projection + fused RoPE/scale/bf16 epilogue + V-transpose -> vt
    gemm4w_kernel<1><<<dim3(3072 / 128, 2048 / 128), 256, 0, stream>>>(
        xb, wqkvT, qkv_bf, 3072, 2048, fc, fs, vt);

    attn_mfma_kernel<<<dim3(NH, L / 64), 256, 0, stream>>>(qkv_bf, vt, ab);

    // out projection -> fp32 output
    gemm4w_kernel<0><<<dim3(2048 / 128, 2048 / 128), 256, 0, stream>>>(
        ab, woT, out, 2048, 2048, nullptr, nullptr, nullptr);
}

// Round 11
// 246.921 us; speedup vs baseline: 1.1679x; 1.1679x over previous
//
#include <hip/hip_runtime.h>
#include <hip/hip_bf16.h>

#define L 2048
#define D 2048
#define NH 32
#define NKV 8
#define HD 64

typedef unsigned short u16;
typedef __attribute__((ext_vector_type(8))) short bf16x8;   // 8 bf16 in 4 VGPRs
typedef __attribute__((ext_vector_type(4))) short bf16x4;   // 4 bf16 in 2 VGPRs
typedef __attribute__((ext_vector_type(4))) float f32x4;

#define QSCALE 0.1803368801f   // 0.125 * log2(e): S comes out in log2 domain

// 16x16x16 bf16 MFMA (K=16): the _1k builtin, called directly (r8-proven).
__device__ __forceinline__ f32x4 mfma16(bf16x4 a, bf16x4 b, f32x4 c) {
    return __builtin_amdgcn_mfma_f32_16x16x16bf16_1k(a, b, c, 0, 0, 0);
}

// Panel layout for GEMM operands: [dim0/128][k/32][128][32] (u16), so one
// 128x32 sub-tile = 8KB contiguous.
#define PANEL_OFF(d0, k) ((((size_t)((d0) >> 7) * 64 + ((k) >> 5)) << 12) + (((d0) & 127) << 5) + ((k) & 31))

__device__ __forceinline__ u16 f2bf(float x) {
    __hip_bfloat16 b = __float2bfloat16(x);
    return *reinterpret_cast<u16*>(&b);
}

// Async global->LDS, 16B per lane. Global src address is PER-LANE; LDS dest
// is wave-uniform base + lane*16.
__device__ __forceinline__ void gload_lds16(const void* g, void* l) {
    __builtin_amdgcn_global_load_lds(
        (const __attribute__((address_space(1))) unsigned int*)g,
        (__attribute__((address_space(3))) unsigned int*)l, 16, 0, 0);
}

// ---------------------------------------------------------------------------
// Fused prep (r10 rewrite, KEPT -- budget says it helped ~14us):
// z=0..3: weight transpose fp32 [2048][C] -> bf16 PANEL, 64x64 tiles,
//         float4 loads, LDS [64][65] fp32 conflict-free transpose,
//         16 elems/thread, 2x bf16x8 panel stores.
// z=4: x cast, 4x float4 per thread.
// ---------------------------------------------------------------------------
__global__ __launch_bounds__(256) void prep_kernel(
    const float* __restrict__ x, u16* __restrict__ xb,
    const float* __restrict__ wq, const float* __restrict__ wk,
    const float* __restrict__ wv, const float* __restrict__ wo,
    u16* __restrict__ wqkvT, u16* __restrict__ woT)
{
    const int z = blockIdx.z;
    const int tid = threadIdx.x;
    if (z == 4) {                                  // cast x -> panels
        const int base = (blockIdx.y * 32 + blockIdx.x) * 1024 + tid;
#pragma unroll
        for (int k = 0; k < 4; ++k) {
            const int i = base + k * 256;          // float4 idx, coalesced
            const int e = i * 4;
            const int row = e >> 11, k0 = e & 2047;
            float4 v = ((const float4*)x)[i];
            ushort4 o;
            o.x = f2bf(v.x); o.y = f2bf(v.y); o.z = f2bf(v.z); o.w = f2bf(v.w);
            *(ushort4*)&xb[PANEL_OFF(row, k0)] = o;
        }
        return;
    }
    const float* src; u16* dst; int C;
    if (z == 0)      { src = wq; dst = wqkvT;                           C = 2048; }
    else if (z == 1) { src = wk; dst = wqkvT + (size_t)2048 * 2048;     C = 512;  }
    else if (z == 2) { src = wv; dst = wqkvT + (size_t)2560 * 2048;     C = 512;  }
    else             { src = wo; dst = woT;                             C = 2048; }
    const int c0 = blockIdx.x * 64;                // n-block (weight col)
    if (c0 >= C) return;
    const int r0 = blockIdx.y * 64;                // k-block (contraction)
    __shared__ float tile[64][65];                 // tile[a][b] = src[r0+a][c0+b]
    {
        const int b4 = (tid & 15) * 4, ty = tid >> 4;
#pragma unroll
        for (int i = 0; i < 4; ++i) {
            const int a = ty + i * 16;
            float4 v = *(const float4*)&src[(size_t)(r0 + a) * C + c0 + b4];
            tile[a][b4] = v.x; tile[a][b4 + 1] = v.y;
            tile[a][b4 + 2] = v.z; tile[a][b4 + 3] = v.w;
        }
    }
    __syncthreads();
    {
        const int j = tid & 63, h16 = (tid >> 6) * 16;   // n-local, k-quarter
        u16 buf[16];
#pragma unroll
        for (int t = 0; t < 16; ++t) buf[t] = f2bf(tile[h16 + t][j]);
        u16* d = &dst[PANEL_OFF(c0 + j, r0 + h16)];      // 16 u16 contiguous
        *(bf16x8*)d       = *(bf16x8*)&buf[0];
        *(bf16x8*)(d + 8) = *(bf16x8*)&buf[8];
    }
}

// ---------------------------------------------------------------------------
// 4-wave 128x128 MFMA GEMM on PANEL-layout operands.
// REVERTED to the r4-r9 proven structure: 4 LDS buffers (64KB -> 2
// blocks/CU), two barriers + vmcnt(8) + lgkmcnt(0) per 64-K period.
// r10's 8-buffer/1-barrier variant is REFUTED: 128KB LDS -> 1 block/CU
// dropped occupancy to 8%, VALUBusy to 12.5%, and L2 panel reuse collapsed
// (FETCH 55->89MB, HBM-visible) -> 84us vs <=57. 2 blocks/CU TLP + L2
// locality beat pipeline depth here.
// ---------------------------------------------------------------------------
#define VT_LDS 72   // u16 stride for V-transpose scratch (144B, 16B-aligned)

template <int MODE>
__global__ __launch_bounds__(256) void gemm4w_kernel(
    const u16* __restrict__ A, const u16* __restrict__ Bt, void* __restrict__ Cout,
    int N, int K, const float* __restrict__ fc, const float* __restrict__ fs,
    u16* __restrict__ vt)
{
    __shared__ __align__(16) u16 As[4][128 * 32];
    __shared__ __align__(16) u16 Bs[4][128 * 32];
    const int tid = threadIdx.x;
    const int w = tid >> 6, lane = tid & 63;

    // bijective XCD-aware block swizzle (both grids have nwg % 8 == 0)
    const int nwg = (int)(gridDim.x * gridDim.y);
    int bid = (int)blockIdx.y * (int)gridDim.x + (int)blockIdx.x;
    bid = (bid & 7) * (nwg >> 3) + (bid >> 3);
    const int m0 = (bid / (int)gridDim.x) * 128, n0 = (bid % (int)gridDim.x) * 128;

    const int l15 = lane & 15, quad = lane >> 4, q8 = quad * 8;
    const int wr = (w >> 1) * 64, wc = (w & 1) * 64;    // wave's C-quadrant
    const int l8 = lane * 8;                            // u16 offset of lane's 16B
    const int wch = w * 1024;                           // wave's 2KB chunk of 8KB sub-tile

    // panel bases: sub-tile s of this block's panels is 4096 u16 at s*4096
    const u16* pa = A  + ((size_t)(m0 >> 7) * (K / 32) << 12);
    const u16* pb = Bt + ((size_t)(n0 >> 7) * (K / 32) << 12);

    f32x4 acc[4][4];
#pragma unroll
    for (int i = 0; i < 4; ++i)
#pragma unroll
        for (int j = 0; j < 4; ++j) acc[i][j] = (f32x4){0.f, 0.f, 0.f, 0.f};

    const int nSub = K / 32;          // 32-K sub-tiles
    const int nOut = nSub / 2;        // wait-periods
    // prologue: subs 0..3 into bufs 0..3, oldest-first (16 DMAs in flight)
#pragma unroll
    for (int s = 0; s < 4; ++s) {
        const size_t so = (size_t)s << 12;
        gload_lds16(pa + so + wch + l8,       &As[s][wch]);
        gload_lds16(pa + so + wch + 512 + l8, &As[s][wch + 512]);
        gload_lds16(pb + so + wch + l8,       &Bs[s][wch]);
        gload_lds16(pb + so + wch + 512 + l8, &Bs[s][wch + 512]);
    }
    for (int it = 0; it < nOut; ++it) {
        const int s0 = 2 * it, cb0 = s0 & 3, cb1 = (s0 + 1) & 3;
        asm volatile("s_waitcnt vmcnt(8)" ::: "memory");   // subs s0,s0+1 done
        asm volatile("s_barrier" ::: "memory");            // ..for all waves
        bf16x8 a0[4], a1[4], b0[4], b1[4];
#pragma unroll
        for (int t = 0; t < 4; ++t) {
            a0[t] = *(const bf16x8*)&As[cb0][(wr + t * 16 + l15) * 32 + q8];
            b0[t] = *(const bf16x8*)&Bs[cb0][(wc + t * 16 + l15) * 32 + q8];
            a1[t] = *(const bf16x8*)&As[cb1][(wr + t * 16 + l15) * 32 + q8];
            b1[t] = *(const bf16x8*)&Bs[cb1][(wc + t * 16 + l15) * 32 + q8];
        }
        asm volatile("s_waitcnt lgkmcnt(0)" ::: "memory"); // reads in regs
        asm volatile("s_barrier" ::: "memory");            // all waves consumed bufs
        {
            const int sp0 = s0 + 4, sp1 = s0 + 5;
            const size_t k0 = (size_t)((sp0 < nSub) ? sp0 : 0) << 12;  // wrap: dummy
            const size_t k1 = (size_t)((sp1 < nSub) ? sp1 : 0) << 12;
            gload_lds16(pa + k0 + wch + l8,       &As[cb0][wch]);
            gload_lds16(pa + k0 + wch + 512 + l8, &As[cb0][wch + 512]);
            gload_lds16(pb + k0 + wch + l8,       &Bs[cb0][wch]);
            gload_lds16(pb + k0 + wch + 512 + l8, &Bs[cb0][wch + 512]);
            gload_lds16(pa + k1 + wch + l8,       &As[cb1][wch]);
            gload_lds16(pa + k1 + wch + 512 + l8, &As[cb1][wch + 512]);
            gload_lds16(pb + k1 + wch + l8,       &Bs[cb1][wch]);
            gload_lds16(pb + k1 + wch + 512 + l8, &Bs[cb1][wch + 512]);
        }
#pragma unroll
        for (int i = 0; i < 4; ++i)
#pragma unroll
            for (int j = 0; j < 4; ++j) {
                acc[i][j] = __builtin_amdgcn_mfma_f32_16x16x32_bf16(a0[i], b0[j], acc[i][j], 0, 0, 0);
                acc[i][j] = __builtin_amdgcn_mfma_f32_16x16x32_bf16(a1[i], b1[j], acc[i][j], 0, 0, 0);
            }
    }

    if (MODE == 0) {
        float* C = (float*)Cout;
#pragma unroll
        for (int i = 0; i < 4; ++i)
#pragma unroll
            for (int j = 0; j < 4; ++j)
#pragma unroll
                for (int r = 0; r < 4; ++r)
                    C[(size_t)(m0 + wr + i * 16 + quad * 4 + r) * N + n0 + wc + j * 16 + l15] = acc[i][j][r];
    } else {
        __syncthreads();                       // loop done everywhere; LDS reusable
        u16* O = (u16*)Cout;
        const int vc0 = n0 + wc;               // wave's first output column
        if (vc0 < 2560) {                      // Q or K region: RoPE + row store
            const float scl = (vc0 < 2048) ? QSCALE : 1.0f;   // q only
            const int odd = l15 & 1;
#pragma unroll
            for (int i = 0; i < 4; ++i)
#pragma unroll
                for (int j = 0; j < 4; ++j)
#pragma unroll
                    for (int r = 0; r < 4; ++r) {
                        const int row = m0 + wr + i * 16 + quad * 4 + r;
                        const int col = vc0 + j * 16 + l15;
                        float v = acc[i][j][r];
                        const int i2 = (j * 16 + l15) >> 1;   // head-dim pair (vc0 is 64-aligned)
                        const float c = fc[row * 32 + i2], s = fs[row * 32 + i2];
                        const float p = __shfl_xor(v, 1);
                        float o = (odd ? (p * s + v * c) : (v * c - p * s)) * scl;
                        O[(size_t)row * 3072 + col] = f2bf(o);
                    }
        } else {                               // V region: transpose -> vt via LDS
            u16* ws_ = (w < 2 ? (u16*)As : (u16*)Bs) + (w & 1) * (64 * VT_LDS);
#pragma unroll
            for (int i = 0; i < 4; ++i)
#pragma unroll
                for (int j = 0; j < 4; ++j)
#pragma unroll
                    for (int r = 0; r < 4; ++r)
                        ws_[(j * 16 + l15) * VT_LDS + i * 16 + quad * 4 + r] = f2bf(acc[i][j][r]);
            // ws_ is [64 vcols][64 seq]; read rows coalesced, write vt rows
#pragma unroll
            for (int t = 0; t < 8; ++t) {
                const int vr = t * 8 + (lane >> 3);
                const int c8 = (lane & 7) * 8;
                bf16x8 vv = *(const bf16x8*)&ws_[vr * VT_LDS + c8];
                *(bf16x8*)&vt[(size_t)(vc0 - 2560 + vr) * 2048 + m0 + wr + c8] = vv;
            }
        }
    }
}

// ---------------------------------------------------------------------------
// MFMA flash attention: r9-passing version, UNCHANGED.
// ---------------------------------------------------------------------------
#define ATT_STEP(CVAL, CB)                                                     \
    {                                                                          \
        gload_lds16(pk0, &Ks[(CB) ^ 1][(w * 16) * 64]);                        \
        gload_lds16(pk1, &Ks[(CB) ^ 1][(w * 16 + 8) * 64]);                    \
        gload_lds16(pv0, &Vs[(CB) ^ 1][(w * 16) * 64]);                        \
        gload_lds16(pv1, &Vs[(CB) ^ 1][(w * 16 + 8) * 64]);                    \
        pk0 += 64 * 3072; pk1 += 64 * 3072; pv0 += 64; pv1 += 64;              \
        asm volatile("s_waitcnt vmcnt(4)" ::: "memory");                       \
        asm volatile("s_barrier" ::: "memory");                                \
        const char* KB = (const char*)Ks + (CB) * 8192;                        \
        const char* VB = (const char*)Vs + (CB) * 8192;                        \
        f32x4 s[4];                                                            \
        __builtin_amdgcn_s_setprio(1);                                         \
        _Pragma("unroll")                                                      \
        for (int kt = 0; kt < 4; ++kt) {                                       \
            bf16x8 b0 = *(const bf16x8*)(KB + kt * 2048 + aK);                 \
            bf16x8 b1 = *(const bf16x8*)(KB + kt * 2048 + aK2);                \
            f32x4 t = (f32x4){0.f, 0.f, 0.f, 0.f};                             \
            t = __builtin_amdgcn_mfma_f32_16x16x32_bf16(b0, qa[0], t, 0, 0, 0);\
            t = __builtin_amdgcn_mfma_f32_16x16x32_bf16(b1, qa[1], t, 0, 0, 0);\
            s[kt] = t;                                                         \
        }                                                                      \
        __builtin_amdgcn_s_setprio(0);                                         \
        if ((CVAL) == tile) {                                                  \
            _Pragma("unroll")                                                  \
            for (int kt = 0; kt < 4; ++kt)                                     \
                _Pragma("unroll")                                              \
                for (int r = 0; r < 4; ++r)                                    \
                    if (kt * 16 + quad * 4 + r > w * 16 + l15)                 \
                        s[kt][r] = -1e30f;                                     \
        }                                                                      \
        float mx = fmaxf(fmaxf(fmaxf(s[0][0], s[0][1]), fmaxf(s[0][2], s[0][3])), \
                         fmaxf(fmaxf(s[1][0], s[1][1]), fmaxf(s[1][2], s[1][3]))); \
        mx = fmaxf(mx, fmaxf(fmaxf(fmaxf(s[2][0], s[2][1]), fmaxf(s[2][2], s[2][3])), \
                             fmaxf(fmaxf(s[3][0], s[3][1]), fmaxf(s[3][2], s[3][3])))); \
        mx = fmaxf(mx, __shfl_xor(mx, 16));                                    \
        mx = fmaxf(mx, __shfl_xor(mx, 32));                                    \
        const bool resc = !__all(mx <= m_run + 8.f);                           \
        float aL = 1.f;                                                        \
        if (resc) {                                                            \
            const float mn = fmaxf(m_run, mx);                                 \
            aL = exp2f(m_run - mn);                                            \
            m_run = mn;                                                        \
        }                                                                      \
        _Pragma("unroll")                                                      \
        for (int kt = 0; kt < 4; ++kt)                                         \
            _Pragma("unroll")                                                  \
            for (int r = 0; r < 4; ++r) s[kt][r] = exp2f(s[kt][r] - m_run);    \
        float rsum = 0.f;                                                      \
        _Pragma("unroll")                                                      \
        for (int kt = 0; kt < 4; ++kt)                                         \
            _Pragma("unroll")                                                  \
            for (int r = 0; r < 4; ++r) rsum += s[kt][r];                      \
        rsum += __shfl_xor(rsum, 16);                                          \
        rsum += __shfl_xor(rsum, 32);                                          \
        l_run = resc ? (l_run * aL + rsum) : (l_run + rsum);                   \
        bf16x4 pbf[4];                                                         \
        _Pragma("unroll")                                                      \
        for (int kt = 0; kt < 4; ++kt) {                                       \
            unsigned int lo, hi;                                               \
            asm("v_cvt_pk_bf16_f32 %0, %1, %2" : "=v"(lo) : "v"(s[kt][0]), "v"(s[kt][1])); \
            asm("v_cvt_pk_bf16_f32 %0, %1, %2" : "=v"(hi) : "v"(s[kt][2]), "v"(s[kt][3])); \
            union { unsigned int u[2]; bf16x4 v; } cv;                         \
            cv.u[0] = lo; cv.u[1] = hi;                                        \
            pbf[kt] = cv.v;                                                    \
        }                                                                      \
        if (resc) {                                                            \
            _Pragma("unroll")                                                  \
            for (int r = 0; r < 4; ++r) {                                      \
                const float aQ = __shfl(aL, (quad << 4) + (quad << 2) + r);    \
                O[0][r] *= aQ; O[1][r] *= aQ; O[2][r] *= aQ; O[3][r] *= aQ;    \
            }                                                                  \
        }                                                                      \
        __builtin_amdgcn_s_setprio(1);                                         \
        _Pragma("unroll")                                                      \
        for (int kt = 0; kt < 4; ++kt) {                                       \
            const int aVk = aV ^ (kt * 32);                                    \
            _Pragma("unroll")                                                  \
            for (int dt = 0; dt < 4; ++dt) {                                   \
                bf16x4 vf = *(const bf16x4*)(VB + dt * 2048 + aVk);            \
                O[dt] = mfma16(pbf[kt], vf, O[dt]);                            \
            }                                                                  \
        }                                                                      \
        __builtin_amdgcn_s_setprio(0);                                         \
        asm volatile("s_barrier" ::: "memory");                                \
    }

__global__ __launch_bounds__(256) void attn_mfma_kernel(
    const u16* __restrict__ qkv,  // [2048][3072] bf16: q|k|v
    const u16* __restrict__ vt,   // [512][2048] bf16 (V^T)
    u16* __restrict__ ab)         // panel-layout bf16 [16][64][128][32]
{
    __shared__ __align__(16) u16 Ks[2][64 * 64];   // linear, swizzled content
    __shared__ __align__(16) u16 Vs[2][64 * 64];

    const int h = blockIdx.x;
    const int tile = (int)gridDim.y - 1 - (int)blockIdx.y;  // big tiles first
    const int gkv = h >> 2;
    const int tid = threadIdx.x;
    const int w = tid >> 6, lane = tid & 63;
    const int l15 = lane & 15, quad = lane >> 4;
    const int q0 = tile * 64 + w * 16;

    // staging geometry (r5): wave w stages rows [w*16, w*16+16) of K and V.
    const int srow = lane >> 3, schunk = lane & 7;
    const int r0_ = w * 16 + srow, r1_ = r0_ + 8;
    const int c0_ = (schunk ^ (r0_ & 7)) * 8, c1_ = (schunk ^ (r1_ & 7)) * 8;

    // DMA source pointers: point at the NEXT tile to prefetch; bumped by
    // constant strides each STEP. Final STEP prefetches one tile past the
    // end -- lands in allocated workspace, never consumed.
    const u16* pk0 = qkv + 2048 + gkv * HD + (size_t)r0_ * 3072 + c0_;
    const u16* pk1 = qkv + 2048 + gkv * HD + (size_t)r1_ * 3072 + c1_;
    const u16* pv0 = vt + (size_t)(gkv * HD + r0_) * 2048 + c0_;
    const u16* pv1 = vt + (size_t)(gkv * HD + r1_) * 2048 + c1_;

    // hoisted per-lane LDS byte-address regs (within one 8KB buffer):
    const int kx = l15 & 7;
    const int aK  = l15 * 128 + ((quad ^ kx) * 16);            // K b128, lo half
    const int aK2 = aK ^ 64;                                   // (quad+4)^kx
    const int aV  = l15 * 128 + (((quad >> 1) ^ kx) * 16) + ((quad & 1) * 8);  // V b64, kt=0

    bf16x8 qa[2];
    {
        const u16* qrow = qkv + (size_t)(q0 + l15) * 3072 + h * HD + quad * 8;
        qa[0] = *(const bf16x8*)(qrow);
        qa[1] = *(const bf16x8*)(qrow + 32);
    }
    f32x4 O[4];
#pragma unroll
    for (int i = 0; i < 4; ++i) O[i] = (f32x4){0.f, 0.f, 0.f, 0.f};
    float m_run = -1e30f;      // softmax side: row l15
    float l_run = 0.f;         // softmax side: row l15 (scalar)

    // prologue: tile 0 into buf 0 (4 DMAs/wave); then bump to tile 1
    gload_lds16(pk0, &Ks[0][(w * 16) * 64]);
    gload_lds16(pk1, &Ks[0][(w * 16 + 8) * 64]);
    gload_lds16(pv0, &Vs[0][(w * 16) * 64]);
    gload_lds16(pv1, &Vs[0][(w * 16 + 8) * 64]);
    pk0 += 64 * 3072; pk1 += 64 * 3072; pv0 += 64; pv1 += 64;

    for (int c = 0; c <= tile; c += 2) {
        ATT_STEP(c, 0)
        if (c + 1 <= tile) {
            ATT_STEP(c + 1, 1)
        }
    }

#pragma unroll
    for (int r = 0; r < 4; ++r) {
        // l for qrow=quad*4+r lives at lane quad*20+r (l15 side -> quad side)
        const float lq = __shfl(l_run, (quad << 4) + (quad << 2) + r);
        const float inv = 1.0f / lq;
        const int q = q0 + quad * 4 + r;
        const int pbase = ((q >> 7) << 18) + ((q & 127) << 5);   // 32-bit panel math
#pragma unroll
        for (int dt = 0; dt < 4; ++dt) {
            const int col = h * HD + dt * 16 + l15;
            ab[pbase + ((col >> 5) << 12) + (col & 31)] = f2bf(O[dt][r] * inv);
        }
    }
}

// ---------------------------------------------------------------------------
extern "C" void kernel_launch(void* const* d_in, const int* in_sizes, int n_in,
                              void* d_out, int out_size, void* d_ws, size_t ws_size,
                              hipStream_t stream)
{
    const float* x  = (const float*)d_in[0];
    const float* wq = (const float*)d_in[1];
    const float* wk = (const float*)d_in[2];
    const float* wv = (const float*)d_in[3];
    const float* wo = (const float*)d_in[4];
    const float* fc = (const float*)d_in[5];
    const float* fs = (const float*)d_in[6];
    // d_in[7] = mask: unused (hard causal == -1e9 additive path in fp32)
    float* out = (float*)d_out;

    // Workspace 50 MB:
    // xb 8MB | wqkvT 12MB | woT 8MB | qkv_bf 12MB | vt 2MB | ab 8MB
    // xb, wqkvT, woT, ab are PANEL layout; qkv_bf, vt plain.
    u16* xb     = (u16*)d_ws;
    u16* wqkvT  = xb     + (size_t)2048 * 2048;
    u16* woT    = wqkvT  + (size_t)3072 * 2048;
    u16* qkv_bf = woT    + (size_t)2048 * 2048;
    u16* vt     = qkv_bf + (size_t)2048 * 3072;
    u16* ab     = vt     + (size_t)512 * 2048;

    // prep: 4 weight transposes + x cast in one dispatch (panel outputs)
    prep_kernel<<<dim3(32, 32, 5), 256, 0, stream>>>(x, xb, wq, wk, wv, wo, wqkvT, woT);

    // QKV projection + fused RoPE/scale/bf16 epilogue + V-transpose -> vt
    gemm4w_kernel<1><<<dim3(3072 / 128, 2048 / 128), 256, 0, stream>>>(
        xb, wqkvT, qkv_bf, 3072, 2048, fc, fs, vt);

    attn_mfma_kernel<<<dim3(NH, L / 64), 256, 0, stream>>>(qkv_bf, vt, ab);

    // out projection -> fp32 output
    gemm4w_kernel<0><<<dim3(2048 / 128, 2048 / 128), 256, 0, stream>>>(
        ab, woT, out, 2048, 2048, nullptr, nullptr, nullptr);
}